// Round 1
// baseline (464.843 us; speedup 1.0000x reference)
//
#include <hip/hip_runtime.h>
#include <hip/hip_bf16.h>

typedef __attribute__((ext_vector_type(8))) short bf16x8;
typedef __attribute__((ext_vector_type(4))) float f32x4;
typedef __attribute__((ext_vector_type(4))) unsigned short us4;

__device__ __forceinline__ unsigned short f2bf(float f) {
    unsigned int u = __builtin_bit_cast(unsigned int, f);
    unsigned int r = (u + 0x7FFFu + ((u >> 16) & 1u)) >> 16;
    return (unsigned short)r;
}
__device__ __forceinline__ float bf2f(unsigned short h) {
    unsigned int u = ((unsigned int)h) << 16;
    return __builtin_bit_cast(float, u);
}

// C[M, ncol] = act(A[M,256] @ W^T + bias) * scale
// W row j comes from W0 (j<256) or W1 (j-256). Out bf16 or f32.
// Tiles: BM=128, BN=64, BK=64. 4 waves, each wave: 32x64 output (2x4 16x16 frags).
template<int OUT_BF16, int RELU>
__global__ __launch_bounds__(256) void gemm_proj(
    const float* __restrict__ A, int M,
    const float* __restrict__ W0, const float* __restrict__ b0,
    const float* __restrict__ W1, const float* __restrict__ b1,
    void* __restrict__ outp, int ncol, float scale)
{
    __shared__ unsigned short As[128 * 64];
    __shared__ unsigned short Bs[64 * 64];
    char* AsB = (char*)As;
    char* BsB = (char*)Bs;

    const int tid = threadIdx.x;
    const int wave = tid >> 6, lane = tid & 63;
    const int m0 = blockIdx.x * 128;
    const int jbase = blockIdx.y * 64;

    f32x4 acc[2][4] = {};

    for (int kk = 0; kk < 256; kk += 64) {
        // stage A tile: 128 rows x 64 cols, fp32 -> bf16, XOR-swizzled LDS
        #pragma unroll
        for (int i = 0; i < 8; ++i) {
            int fidx = tid + i * 256;
            int row = fidx >> 4;
            int col4 = (fidx & 15) << 2;
            const float4 v = *(const float4*)(A + (size_t)(m0 + row) * 256 + kk + col4);
            us4 h; h.x = f2bf(v.x); h.y = f2bf(v.y); h.z = f2bf(v.z); h.w = f2bf(v.w);
            int byte = row * 128 + col4 * 2;
            *(us4*)(AsB + (byte ^ ((row & 7) << 4))) = h;
        }
        // stage B tile: 64 weight rows (output cols) x 64 k
        #pragma unroll
        for (int i = 0; i < 4; ++i) {
            int fidx = tid + i * 256;
            int row = fidx >> 4;
            int col4 = (fidx & 15) << 2;
            int j = jbase + row;
            const float* W = (j < 256) ? (W0 + (size_t)j * 256) : (W1 + (size_t)(j - 256) * 256);
            const float4 v = *(const float4*)(W + kk + col4);
            us4 h; h.x = f2bf(v.x); h.y = f2bf(v.y); h.z = f2bf(v.z); h.w = f2bf(v.w);
            int byte = row * 128 + col4 * 2;
            *(us4*)(BsB + (byte ^ ((row & 7) << 4))) = h;
        }
        __syncthreads();
        #pragma unroll
        for (int k2 = 0; k2 < 2; ++k2) {
            const int kbyte = k2 * 64 + ((lane >> 4) << 4);
            bf16x8 af[2];
            #pragma unroll
            for (int mi = 0; mi < 2; ++mi) {
                int row = wave * 32 + mi * 16 + (lane & 15);
                int byte = row * 128 + kbyte;
                af[mi] = *(const bf16x8*)(AsB + (byte ^ ((row & 7) << 4)));
            }
            #pragma unroll
            for (int ni = 0; ni < 4; ++ni) {
                int row = ni * 16 + (lane & 15);
                int byte = row * 128 + kbyte;
                bf16x8 bfr = *(const bf16x8*)(BsB + (byte ^ ((row & 7) << 4)));
                #pragma unroll
                for (int mi = 0; mi < 2; ++mi)
                    acc[mi][ni] = __builtin_amdgcn_mfma_f32_16x16x32_bf16(af[mi], bfr, acc[mi][ni], 0, 0, 0);
            }
        }
        __syncthreads();
    }

    // epilogue: bias + relu + scale, store
    #pragma unroll
    for (int ni = 0; ni < 4; ++ni) {
        int col = ni * 16 + (lane & 15);
        int j = jbase + col;
        float bias = (j < 256) ? b0[j] : b1[j - 256];
        #pragma unroll
        for (int mi = 0; mi < 2; ++mi) {
            int rbase = m0 + wave * 32 + mi * 16 + ((lane >> 4) << 2);
            #pragma unroll
            for (int r = 0; r < 4; ++r) {
                float v = acc[mi][ni][r] + bias;
                if (RELU) v = fmaxf(v, 0.f);
                v *= scale;
                size_t off = (size_t)(rbase + r) * ncol + j;
                if (OUT_BF16) ((unsigned short*)outp)[off] = f2bf(v);
                else ((float*)outp)[off] = v;
            }
        }
    }
}

// One block per sample. 4 waves = 4 heads. t = head*64 + d.
__global__ __launch_bounds__(256) void attn_kernel(
    const float* __restrict__ Q, const unsigned short* __restrict__ KV,
    const int* __restrict__ starts, const int* __restrict__ ends,
    float* __restrict__ out)
{
    const int b = blockIdx.x;
    const int t = threadIdx.x;
    const int wave = t >> 6, lane = t & 63;
    const int start = starts[b];
    const int len = ends[b] - start;   // 1..64

    __shared__ float sc[4][64];

    const float qv = Q[(size_t)b * 256 + t];

    // scores: one wave-reduce per neighbor
    for (int m = 0; m < len; ++m) {
        float kvf = bf2f(KV[(size_t)(start + m) * 512 + t]);
        float p = qv * kvf;
        #pragma unroll
        for (int off = 32; off; off >>= 1) p += __shfl_down(p, off);
        if (lane == 0) sc[wave][m] = p;
    }

    // softmax across this wave's 64 score slots (lane m holds score m)
    float s = (lane < len) ? sc[wave][lane] : -3.0e38f;
    float mx = s;
    #pragma unroll
    for (int off = 32; off; off >>= 1) mx = fmaxf(mx, __shfl_xor(mx, off));
    float e = (lane < len) ? __expf(s - mx) : 0.f;
    float sum = e;
    #pragma unroll
    for (int off = 32; off; off >>= 1) sum += __shfl_xor(sum, off);
    sc[wave][lane] = e / sum;   // reuse as attention weights

    // PV accumulate
    float acc = 0.f;
    for (int m = 0; m < len; ++m) {
        float a = sc[wave][m];
        float vv = bf2f(KV[(size_t)(start + m) * 512 + 256 + t]);
        acc += a * vv;
    }
    out[(size_t)b * 256 + t] = acc;
}

extern "C" void kernel_launch(void* const* d_in, const int* in_sizes, int n_in,
                              void* d_out, int out_size, void* d_ws, size_t ws_size,
                              hipStream_t stream) {
    const float* enc    = (const float*)d_in[0];
    const float* social = (const float*)d_in[1];
    const float* Wq = (const float*)d_in[2];
    const float* bq = (const float*)d_in[3];
    const float* Wk = (const float*)d_in[4];
    const float* bk = (const float*)d_in[5];
    const float* Wv = (const float*)d_in[6];
    const float* bv = (const float*)d_in[7];
    const float* Wf = (const float*)d_in[8];
    const float* bf = (const float*)d_in[9];
    const int* st = (const int*)d_in[10];
    const int* en = (const int*)d_in[11];
    (void)in_sizes; (void)n_in; (void)out_size; (void)ws_size;

    char* ws = (char*)d_ws;
    unsigned short* KV = (unsigned short*)ws;                      // 131072*512*2 = 128 MB
    float* Qb    = (float*)(ws + 134217728);                       // 4 MB
    float* attnb = (float*)(ws + 134217728 + 4194304);             // 4 MB
    float* outf  = (float*)d_out;

    dim3 blk(256);
    // K and V fused: cols 0..255 = relu(social@Wk^T+bk), 256..511 = relu(social@Wv^T+bv)
    gemm_proj<1, 1><<<dim3(1024, 8), blk, 0, stream>>>(social, 131072, Wk, bk, Wv, bv, KV, 512, 1.0f);
    // Q = relu(enc@Wq^T+bq) / 16
    gemm_proj<0, 1><<<dim3(32, 4), blk, 0, stream>>>(enc, 4096, Wq, bq, nullptr, nullptr, Qb, 256, 0.0625f);
    attn_kernel<<<dim3(4096), blk, 0, stream>>>(Qb, KV, st, en, attnb);
    // final = attn_out @ Wf^T + bf
    gemm_proj<0, 0><<<dim3(32, 4), blk, 0, stream>>>(attnb, 4096, Wf, bf, nullptr, nullptr, outf, 256, 1.0f);
}

// Round 2
// 343.435 us; speedup vs baseline: 1.3535x; 1.3535x over previous
//
#include <hip/hip_runtime.h>
#include <hip/hip_bf16.h>

typedef __attribute__((ext_vector_type(8))) short bf16x8;
typedef __attribute__((ext_vector_type(4))) float f32x4;
typedef __attribute__((ext_vector_type(4))) unsigned short us4;

__device__ __forceinline__ unsigned short f2bf(float f) {
    unsigned int u = __builtin_bit_cast(unsigned int, f);
    unsigned int r = (u + 0x7FFFu + ((u >> 16) & 1u)) >> 16;
    return (unsigned short)r;
}
__device__ __forceinline__ float bf2f(unsigned short h) {
    unsigned int u = ((unsigned int)h) << 16;
    return __builtin_bit_cast(float, u);
}

__device__ __forceinline__ void gload_lds16(const void* g, void* l) {
    __builtin_amdgcn_global_load_lds(
        (const __attribute__((address_space(1))) unsigned int*)g,
        (__attribute__((address_space(3))) unsigned int*)l, 16, 0, 0);
}

// Pack Wk||Wv (fp32 [256,256] each) into bf16, tiled per K-step (64 k) with the
// LDS XOR-swizzle baked in, so the GEMM can global_load_lds it linearly.
__global__ __launch_bounds__(256) void pack_w(
    const float* __restrict__ Wk, const float* __restrict__ Wv,
    unsigned short* __restrict__ Wp)
{
    int j = blockIdx.x;      // output col 0..511
    int k = threadIdx.x;     // k 0..255
    float v = (j < 256) ? Wk[(size_t)j * 256 + k] : Wv[(size_t)(j - 256) * 256 + k];
    int tk = k >> 6;
    int byte = (j * 128 + (k & 63) * 2) ^ ((j & 7) << 4);
    *(unsigned short*)((char*)Wp + tk * 65536 + byte) = f2bf(v);
}

// KV[m, 0..255]=relu(social@Wk^T+bk), KV[m,256..511]=relu(social@Wv^T+bv), bf16.
// BM=64, BN=512 (A read exactly once), BK=64. 4 waves; wave w owns cols w*128..+128.
__global__ __launch_bounds__(256, 2) void kv_gemm(
    const float* __restrict__ A, const unsigned short* __restrict__ Wp,
    const float* __restrict__ bk, const float* __restrict__ bv,
    unsigned short* __restrict__ KV)
{
    __shared__ unsigned short As[64 * 64];    // 8 KB swizzled
    __shared__ unsigned short Bs[512 * 64];   // 64 KB prepacked-swizzled
    char* AsB = (char*)As;
    char* BsB = (char*)Bs;

    const int tid = threadIdx.x;
    const int wave = tid >> 6, lane = tid & 63;
    const int m0 = blockIdx.x * 64;

    f32x4 acc[4][8] = {};

    for (int tk = 0; tk < 4; ++tk) {
        // stage B: 64 KB via async global->LDS, source already bf16+swizzled
        const char* src = (const char*)Wp + tk * 65536;
        #pragma unroll
        for (int i = 0; i < 16; ++i) {
            int off = (tid + i * 256) * 16;
            gload_lds16(src + off, BsB + off);
        }
        // stage A: 64 rows x 64 k fp32 -> bf16, swizzled
        #pragma unroll
        for (int i = 0; i < 4; ++i) {
            int fidx = tid + i * 256;
            int row = fidx >> 4;
            int col4 = (fidx & 15) << 2;
            float4 v = *(const float4*)(A + (size_t)(m0 + row) * 256 + tk * 64 + col4);
            us4 h; h.x = f2bf(v.x); h.y = f2bf(v.y); h.z = f2bf(v.z); h.w = f2bf(v.w);
            int byte = row * 128 + col4 * 2;
            *(us4*)(AsB + (byte ^ ((row & 7) << 4))) = h;
        }
        __syncthreads();
        #pragma unroll
        for (int k2 = 0; k2 < 2; ++k2) {
            const int kbyte = k2 * 64 + ((lane >> 4) << 4);
            bf16x8 af[4];
            #pragma unroll
            for (int mi = 0; mi < 4; ++mi) {
                int row = mi * 16 + (lane & 15);
                int byte = row * 128 + kbyte;
                af[mi] = *(const bf16x8*)(AsB + (byte ^ ((row & 7) << 4)));
            }
            #pragma unroll
            for (int ni = 0; ni < 8; ++ni) {
                int j = wave * 128 + ni * 16 + (lane & 15);
                int byte = j * 128 + kbyte;
                bf16x8 bfr = *(const bf16x8*)(BsB + (byte ^ ((j & 7) << 4)));
                #pragma unroll
                for (int mi = 0; mi < 4; ++mi)
                    acc[mi][ni] = __builtin_amdgcn_mfma_f32_16x16x32_bf16(af[mi], bfr, acc[mi][ni], 0, 0, 0);
            }
        }
        __syncthreads();
    }

    #pragma unroll
    for (int ni = 0; ni < 8; ++ni) {
        int col = wave * 128 + ni * 16 + (lane & 15);
        float bias = (col < 256) ? bk[col] : bv[col - 256];
        #pragma unroll
        for (int mi = 0; mi < 4; ++mi) {
            int rbase = m0 + mi * 16 + ((lane >> 4) << 2);
            #pragma unroll
            for (int r = 0; r < 4; ++r) {
                float v = fmaxf(acc[mi][ni][r] + bias, 0.f);
                KV[(size_t)(rbase + r) * 512 + col] = f2bf(v);
            }
        }
    }
}

// Generic small GEMM with fused bias/relu/scale (used for Q and final proj).
// C[M, ncol] = act(A[M,256] @ W^T + b) * scale; BM=128, BN=64, BK=64.
template<int OUT_BF16, int RELU>
__global__ __launch_bounds__(256) void gemm_proj(
    const float* __restrict__ A, int M,
    const float* __restrict__ W0, const float* __restrict__ b0,
    const float* __restrict__ W1, const float* __restrict__ b1,
    void* __restrict__ outp, int ncol, float scale)
{
    __shared__ unsigned short As[128 * 64];
    __shared__ unsigned short Bs[64 * 64];
    char* AsB = (char*)As;
    char* BsB = (char*)Bs;

    const int tid = threadIdx.x;
    const int wave = tid >> 6, lane = tid & 63;
    const int m0 = blockIdx.x * 128;
    const int jbase = blockIdx.y * 64;

    f32x4 acc[2][4] = {};

    for (int kk = 0; kk < 256; kk += 64) {
        #pragma unroll
        for (int i = 0; i < 8; ++i) {
            int fidx = tid + i * 256;
            int row = fidx >> 4;
            int col4 = (fidx & 15) << 2;
            const float4 v = *(const float4*)(A + (size_t)(m0 + row) * 256 + kk + col4);
            us4 h; h.x = f2bf(v.x); h.y = f2bf(v.y); h.z = f2bf(v.z); h.w = f2bf(v.w);
            int byte = row * 128 + col4 * 2;
            *(us4*)(AsB + (byte ^ ((row & 7) << 4))) = h;
        }
        #pragma unroll
        for (int i = 0; i < 4; ++i) {
            int fidx = tid + i * 256;
            int row = fidx >> 4;
            int col4 = (fidx & 15) << 2;
            int j = jbase + row;
            const float* W = (j < 256) ? (W0 + (size_t)j * 256) : (W1 + (size_t)(j - 256) * 256);
            const float4 v = *(const float4*)(W + kk + col4);
            us4 h; h.x = f2bf(v.x); h.y = f2bf(v.y); h.z = f2bf(v.z); h.w = f2bf(v.w);
            int byte = row * 128 + col4 * 2;
            *(us4*)(BsB + (byte ^ ((row & 7) << 4))) = h;
        }
        __syncthreads();
        #pragma unroll
        for (int k2 = 0; k2 < 2; ++k2) {
            const int kbyte = k2 * 64 + ((lane >> 4) << 4);
            bf16x8 af[2];
            #pragma unroll
            for (int mi = 0; mi < 2; ++mi) {
                int row = wave * 32 + mi * 16 + (lane & 15);
                int byte = row * 128 + kbyte;
                af[mi] = *(const bf16x8*)(AsB + (byte ^ ((row & 7) << 4)));
            }
            #pragma unroll
            for (int ni = 0; ni < 4; ++ni) {
                int row = ni * 16 + (lane & 15);
                int byte = row * 128 + kbyte;
                bf16x8 bfr = *(const bf16x8*)(BsB + (byte ^ ((row & 7) << 4)));
                #pragma unroll
                for (int mi = 0; mi < 2; ++mi)
                    acc[mi][ni] = __builtin_amdgcn_mfma_f32_16x16x32_bf16(af[mi], bfr, acc[mi][ni], 0, 0, 0);
            }
        }
        __syncthreads();
    }

    #pragma unroll
    for (int ni = 0; ni < 4; ++ni) {
        int col = ni * 16 + (lane & 15);
        int j = jbase + col;
        float bias = (j < 256) ? b0[j] : b1[j - 256];
        #pragma unroll
        for (int mi = 0; mi < 2; ++mi) {
            int rbase = m0 + wave * 32 + mi * 16 + ((lane >> 4) << 2);
            #pragma unroll
            for (int r = 0; r < 4; ++r) {
                float v = acc[mi][ni][r] + bias;
                if (RELU) v = fmaxf(v, 0.f);
                v *= scale;
                size_t off = (size_t)(rbase + r) * ncol + j;
                if (OUT_BF16) ((unsigned short*)outp)[off] = f2bf(v);
                else ((float*)outp)[off] = v;
            }
        }
    }
}

// 1 block/sample, wave = head. Lane-per-neighbor scores (no per-neighbor reduce),
// butterfly softmax, coalesced PV.
__global__ __launch_bounds__(256) void attn_kernel(
    const float* __restrict__ Q, const unsigned short* __restrict__ KV,
    const int* __restrict__ starts, const int* __restrict__ ends,
    float* __restrict__ out)
{
    const int b = blockIdx.x;
    const int t = threadIdx.x;
    const int h = t >> 6, lane = t & 63;
    const int start = starts[b];
    const int len = ends[b] - start;   // 1..64

    __shared__ float qs[256];
    __shared__ float aw[4][64];
    qs[t] = Q[(size_t)b * 256 + t];
    __syncthreads();

    // score for neighbor `lane` of head h
    float s = -3.0e38f;
    if (lane < len) {
        s = 0.f;
        const unsigned short* krow = KV + (size_t)(start + lane) * 512 + h * 64;
        #pragma unroll
        for (int d8 = 0; d8 < 8; ++d8) {
            bf16x8 kv = *(const bf16x8*)(krow + d8 * 8);
            #pragma unroll
            for (int jj = 0; jj < 8; ++jj)
                s += qs[h * 64 + d8 * 8 + jj] * bf2f((unsigned short)kv[jj]);
        }
    }
    float mx = s;
    #pragma unroll
    for (int off = 32; off; off >>= 1) mx = fmaxf(mx, __shfl_xor(mx, off));
    float e = (lane < len) ? __expf(s - mx) : 0.f;
    float sum = e;
    #pragma unroll
    for (int off = 32; off; off >>= 1) sum += __shfl_xor(sum, off);
    aw[h][lane] = e / sum;
    __syncthreads();

    // PV: lane = dim d within head; coalesced 128B row reads per wave
    float acc = 0.f;
    const unsigned short* vbase = KV + (size_t)start * 512 + 256 + h * 64 + lane;
    for (int m = 0; m < len; ++m)
        acc += aw[h][m] * bf2f(vbase[(size_t)m * 512]);
    out[(size_t)b * 256 + t] = acc;
}

extern "C" void kernel_launch(void* const* d_in, const int* in_sizes, int n_in,
                              void* d_out, int out_size, void* d_ws, size_t ws_size,
                              hipStream_t stream) {
    const float* enc    = (const float*)d_in[0];
    const float* social = (const float*)d_in[1];
    const float* Wq = (const float*)d_in[2];
    const float* bq = (const float*)d_in[3];
    const float* Wk = (const float*)d_in[4];
    const float* bk = (const float*)d_in[5];
    const float* Wv = (const float*)d_in[6];
    const float* bv = (const float*)d_in[7];
    const float* Wf = (const float*)d_in[8];
    const float* bf = (const float*)d_in[9];
    const int* st = (const int*)d_in[10];
    const int* en = (const int*)d_in[11];
    (void)in_sizes; (void)n_in; (void)out_size; (void)ws_size;

    char* ws = (char*)d_ws;
    unsigned short* KV = (unsigned short*)ws;                       // 128 MB
    float* Qb    = (float*)(ws + 134217728);                        // 4 MB
    float* attnb = (float*)(ws + 134217728 + 4194304);              // 4 MB
    // W_pack aliases attnb: pack -> kv_gemm reads it -> attn overwrites later
    unsigned short* Wp = (unsigned short*)attnb;
    float* outf  = (float*)d_out;

    dim3 blk(256);
    pack_w<<<dim3(512), blk, 0, stream>>>(Wk, Wv, Wp);
    kv_gemm<<<dim3(2048), blk, 0, stream>>>(social, Wp, bk, bv, KV);
    gemm_proj<0, 1><<<dim3(32, 4), blk, 0, stream>>>(enc, 4096, Wq, bq, nullptr, nullptr, Qb, 256, 0.0625f);
    attn_kernel<<<dim3(4096), blk, 0, stream>>>(Qb, KV, st, en, attnb);
    gemm_proj<0, 0><<<dim3(32, 4), blk, 0, stream>>>(attnb, 4096, Wf, bf, nullptr, nullptr, outf, 256, 1.0f);
}

// Round 3
// 318.558 us; speedup vs baseline: 1.4592x; 1.0781x over previous
//
#include <hip/hip_runtime.h>
#include <hip/hip_bf16.h>

typedef __attribute__((ext_vector_type(8))) short bf16x8;
typedef __attribute__((ext_vector_type(4))) float f32x4;
typedef __attribute__((ext_vector_type(4))) unsigned short us4;

__device__ __forceinline__ unsigned short f2bf(float f) {
    unsigned int u = __builtin_bit_cast(unsigned int, f);
    unsigned int r = (u + 0x7FFFu + ((u >> 16) & 1u)) >> 16;
    return (unsigned short)r;
}
__device__ __forceinline__ float bf2f(unsigned short h) {
    unsigned int u = ((unsigned int)h) << 16;
    return __builtin_bit_cast(float, u);
}

__device__ __forceinline__ void gload_lds16(const void* g, void* l) {
    __builtin_amdgcn_global_load_lds(
        (const __attribute__((address_space(1))) unsigned int*)g,
        (__attribute__((address_space(3))) unsigned int*)l, 16, 0, 0);
}

// ---------------------------------------------------------------------------
// KV projection, register-resident weights.
// KV[m,0..255]=relu(social@Wk^T+bk), KV[m,256..511]=relu(social@Wv^T+bv), bf16.
// 256 blocks x 512 threads (8 waves). Wave w owns output cols [w*64, w*64+64).
// B-fragments for full K=256 held in 128 VGPRs/lane, loaded once from L2.
// A staged in LDS 32 rows/tile, double-buffered; 16 tiles per block.
// ---------------------------------------------------------------------------
__global__ __launch_bounds__(512, 2) void kv_gemm_rb(
    const float* __restrict__ A,
    const float* __restrict__ Wk, const float* __restrict__ bk,
    const float* __restrict__ Wv, const float* __restrict__ bv,
    unsigned short* __restrict__ KV)
{
    __shared__ unsigned short Abuf[2][32 * 256];   // 2 x 16 KB, swizzled bf16

    const int tid = threadIdx.x;
    const int wave = tid >> 6, lane = tid & 63;
    const size_t mb = (size_t)blockIdx.x * 512;

    // ---- load B fragments to registers (once) ----
    bf16x8 bfrag[4][8];          // [ni][ks]
    float biasv[4];
    #pragma unroll
    for (int ni = 0; ni < 4; ++ni) {
        int col = wave * 64 + ni * 16 + (lane & 15);
        const float* Wr = (col < 256) ? (Wk + (size_t)col * 256)
                                      : (Wv + (size_t)(col - 256) * 256);
        biasv[ni] = (col < 256) ? bk[col] : bv[col - 256];
        #pragma unroll
        for (int ks = 0; ks < 8; ++ks) {
            int k0 = ks * 32 + ((lane >> 4) << 3);
            float4 x = *(const float4*)(Wr + k0);
            float4 y = *(const float4*)(Wr + k0 + 4);
            bf16x8 f;
            f[0] = (short)f2bf(x.x); f[1] = (short)f2bf(x.y);
            f[2] = (short)f2bf(x.z); f[3] = (short)f2bf(x.w);
            f[4] = (short)f2bf(y.x); f[5] = (short)f2bf(y.y);
            f[6] = (short)f2bf(y.z); f[7] = (short)f2bf(y.w);
            bfrag[ni][ks] = f;
        }
    }

    // ---- prologue: stage tile 0 ----
    {
        const int row = tid >> 4, seg = tid & 15;
        const float* src = A + (mb + row) * 256 + seg * 16;
        float4 a0 = *(const float4*)(src + 0);
        float4 a1 = *(const float4*)(src + 4);
        float4 a2 = *(const float4*)(src + 8);
        float4 a3 = *(const float4*)(src + 12);
        us4 h0, h1, h2, h3;
        h0.x=f2bf(a0.x); h0.y=f2bf(a0.y); h0.z=f2bf(a0.z); h0.w=f2bf(a0.w);
        h1.x=f2bf(a1.x); h1.y=f2bf(a1.y); h1.z=f2bf(a1.z); h1.w=f2bf(a1.w);
        h2.x=f2bf(a2.x); h2.y=f2bf(a2.y); h2.z=f2bf(a2.z); h2.w=f2bf(a2.w);
        h3.x=f2bf(a3.x); h3.y=f2bf(a3.y); h3.z=f2bf(a3.z); h3.w=f2bf(a3.w);
        char* dst = (char*)Abuf[0];
        int byte0 = row * 512 + seg * 32;
        int sw = (row & 7) << 4;
        *(us4*)(dst + ((byte0 +  0) ^ sw)) = h0;
        *(us4*)(dst + ((byte0 + 16) ^ sw)) = h1;  // note 16B slots XOR independently
        // byte0+16 has bit4 set; XOR with sw (bit4..6) stays within the 128B window
        *(us4*)(dst + ((byte0 + 0 + 16) ^ sw)) = h1;
        // (the duplicate line above is harmless overwrite of same address)
        char* d2 = dst;
        *(us4*)(d2 + ((byte0 + 0) ^ sw)) = h0;
        *(us4*)(d2 + ((byte0 + 16) ^ sw)) = h1;
        // second 32B half: elements 8..15 live at byte0+16..31? No:
        // 16 floats -> 16 bf16 = 32 bytes total: h0,h1 = first 16B? Fix layout:
        // bytes [byte0, byte0+32): h0 at +0 (8B)?? us4 = 8 bytes.
        // Correct packing: 16 shorts = 32B = 4 us4 of 8B each.
        *(us4*)(d2 + ((byte0 +  0) ^ sw)) = h0;
        *(us4*)(d2 + ((byte0 +  8) ^ sw)) = h1;
        *(us4*)(d2 + ((byte0 + 16) ^ sw)) = h2;
        *(us4*)(d2 + ((byte0 + 24) ^ sw)) = h3;
    }
    __syncthreads();

    // ---- main loop over 16 M-tiles ----
    for (int t = 0; t < 16; ++t) {
        const int cur = t & 1;
        const bool pf = (t + 1) < 16;
        float4 a0, a1, a2, a3;
        if (pf) {
            const int row = tid >> 4, seg = tid & 15;
            const float* src = A + (mb + (t + 1) * 32 + row) * 256 + seg * 16;
            a0 = *(const float4*)(src + 0);
            a1 = *(const float4*)(src + 4);
            a2 = *(const float4*)(src + 8);
            a3 = *(const float4*)(src + 12);
        }

        // compute tile t
        f32x4 acc[2][4] = {};
        const char* Ab = (const char*)Abuf[cur];
        #pragma unroll
        for (int ks = 0; ks < 8; ++ks) {
            bf16x8 af[2];
            #pragma unroll
            for (int mi = 0; mi < 2; ++mi) {
                int row = mi * 16 + (lane & 15);
                int byte = row * 512 + ks * 64 + ((lane >> 4) << 4);
                af[mi] = *(const bf16x8*)(Ab + (byte ^ ((row & 7) << 4)));
            }
            #pragma unroll
            for (int ni = 0; ni < 4; ++ni)
                #pragma unroll
                for (int mi = 0; mi < 2; ++mi)
                    acc[mi][ni] = __builtin_amdgcn_mfma_f32_16x16x32_bf16(
                        af[mi], bfrag[ni][ks], acc[mi][ni], 0, 0, 0);
        }

        // epilogue: bias + relu -> bf16 stores
        #pragma unroll
        for (int ni = 0; ni < 4; ++ni) {
            int col = wave * 64 + ni * 16 + (lane & 15);
            #pragma unroll
            for (int mi = 0; mi < 2; ++mi) {
                size_t rbase = mb + (size_t)t * 32 + mi * 16 + ((lane >> 4) << 2);
                #pragma unroll
                for (int r = 0; r < 4; ++r) {
                    float v = fmaxf(acc[mi][ni][r] + biasv[ni], 0.f);
                    KV[(rbase + r) * 512 + col] = f2bf(v);
                }
            }
        }

        if (pf) {
            const int row = tid >> 4, seg = tid & 15;
            us4 h0, h1, h2, h3;
            h0.x=f2bf(a0.x); h0.y=f2bf(a0.y); h0.z=f2bf(a0.z); h0.w=f2bf(a0.w);
            h1.x=f2bf(a1.x); h1.y=f2bf(a1.y); h1.z=f2bf(a1.z); h1.w=f2bf(a1.w);
            h2.x=f2bf(a2.x); h2.y=f2bf(a2.y); h2.z=f2bf(a2.z); h2.w=f2bf(a2.w);
            h3.x=f2bf(a3.x); h3.y=f2bf(a3.y); h3.z=f2bf(a3.z); h3.w=f2bf(a3.w);
            char* dst = (char*)Abuf[cur ^ 1];
            int byte0 = row * 512 + seg * 32;
            int sw = (row & 7) << 4;
            *(us4*)(dst + ((byte0 +  0) ^ sw)) = h0;
            *(us4*)(dst + ((byte0 +  8) ^ sw)) = h1;
            *(us4*)(dst + ((byte0 + 16) ^ sw)) = h2;
            *(us4*)(dst + ((byte0 + 24) ^ sw)) = h3;
        }
        __syncthreads();
    }
}

// ---------------------------------------------------------------------------
// Small GEMM with fused bias/relu/scale (Q and final projections).
// ---------------------------------------------------------------------------
template<int OUT_BF16, int RELU>
__global__ __launch_bounds__(256) void gemm_proj(
    const float* __restrict__ A, int M,
    const float* __restrict__ W0, const float* __restrict__ b0,
    const float* __restrict__ W1, const float* __restrict__ b1,
    void* __restrict__ outp, int ncol, float scale)
{
    __shared__ unsigned short As[128 * 64];
    __shared__ unsigned short Bs[64 * 64];
    char* AsB = (char*)As;
    char* BsB = (char*)Bs;

    const int tid = threadIdx.x;
    const int wave = tid >> 6, lane = tid & 63;
    const int m0 = blockIdx.x * 128;
    const int jbase = blockIdx.y * 64;

    f32x4 acc[2][4] = {};

    for (int kk = 0; kk < 256; kk += 64) {
        #pragma unroll
        for (int i = 0; i < 8; ++i) {
            int fidx = tid + i * 256;
            int row = fidx >> 4;
            int col4 = (fidx & 15) << 2;
            const float4 v = *(const float4*)(A + (size_t)(m0 + row) * 256 + kk + col4);
            us4 h; h.x = f2bf(v.x); h.y = f2bf(v.y); h.z = f2bf(v.z); h.w = f2bf(v.w);
            int byte = row * 128 + col4 * 2;
            *(us4*)(AsB + (byte ^ ((row & 7) << 4))) = h;
        }
        #pragma unroll
        for (int i = 0; i < 4; ++i) {
            int fidx = tid + i * 256;
            int row = fidx >> 4;
            int col4 = (fidx & 15) << 2;
            int j = jbase + row;
            const float* W = (j < 256) ? (W0 + (size_t)j * 256) : (W1 + (size_t)(j - 256) * 256);
            const float4 v = *(const float4*)(W + kk + col4);
            us4 h; h.x = f2bf(v.x); h.y = f2bf(v.y); h.z = f2bf(v.z); h.w = f2bf(v.w);
            int byte = row * 128 + col4 * 2;
            *(us4*)(BsB + (byte ^ ((row & 7) << 4))) = h;
        }
        __syncthreads();
        #pragma unroll
        for (int k2 = 0; k2 < 2; ++k2) {
            const int kbyte = k2 * 64 + ((lane >> 4) << 4);
            bf16x8 af[2];
            #pragma unroll
            for (int mi = 0; mi < 2; ++mi) {
                int row = wave * 32 + mi * 16 + (lane & 15);
                int byte = row * 128 + kbyte;
                af[mi] = *(const bf16x8*)(AsB + (byte ^ ((row & 7) << 4)));
            }
            #pragma unroll
            for (int ni = 0; ni < 4; ++ni) {
                int row = ni * 16 + (lane & 15);
                int byte = row * 128 + kbyte;
                bf16x8 bfr = *(const bf16x8*)(BsB + (byte ^ ((row & 7) << 4)));
                #pragma unroll
                for (int mi = 0; mi < 2; ++mi)
                    acc[mi][ni] = __builtin_amdgcn_mfma_f32_16x16x32_bf16(af[mi], bfr, acc[mi][ni], 0, 0, 0);
            }
        }
        __syncthreads();
    }

    #pragma unroll
    for (int ni = 0; ni < 4; ++ni) {
        int col = ni * 16 + (lane & 15);
        int j = jbase + col;
        float bias = (j < 256) ? b0[j] : b1[j - 256];
        #pragma unroll
        for (int mi = 0; mi < 2; ++mi) {
            int rbase = m0 + wave * 32 + mi * 16 + ((lane >> 4) << 2);
            #pragma unroll
            for (int r = 0; r < 4; ++r) {
                float v = acc[mi][ni][r] + bias;
                if (RELU) v = fmaxf(v, 0.f);
                v *= scale;
                size_t off = (size_t)(rbase + r) * ncol + j;
                if (OUT_BF16) ((unsigned short*)outp)[off] = f2bf(v);
                else ((float*)outp)[off] = v;
            }
        }
    }
}

// ---------------------------------------------------------------------------
// Attention: 1 block/sample, wave=head. Full 64-row KV segment staged to LDS
// via global_load_lds (1 KB per instruction, pre-swizzled source). Score with
// lane=neighbor from swizzled ds_read_b128; butterfly softmax; PV split into
// two 32-neighbor halves with packed u32 reads + one shfl_xor(32).
// Dynamic LDS: kv[65536] + aw[4][64] f32 + qs[256] f32 = 67584 B.
// ---------------------------------------------------------------------------
__global__ __launch_bounds__(256) void attn_kernel(
    const float* __restrict__ Q, const unsigned short* __restrict__ KV,
    const int* __restrict__ starts, const int* __restrict__ ends,
    float* __restrict__ out)
{
    extern __shared__ char lds[];
    char* kv = lds;                         // 64 KB
    float* awl = (float*)(lds + 65536);     // 4*64 floats
    float* qs  = (float*)(lds + 65536 + 1024);  // 256 floats

    const int bid = blockIdx.x;
    const int b = ((bid & 7) << 9) + (bid >> 3);   // XCD-chunked swizzle (4096 = 8*512)
    const int t = threadIdx.x;
    const int h = t >> 6, ln = t & 63;
    const int start = starts[b];
    const int len = ends[b] - start;   // 1..64; rows start..start+63 always in-bounds

    // stage: wave w stages rows [w*16, w*16+16), one 1KB row per gload_lds
    #pragma unroll
    for (int i = 0; i < 16; ++i) {
        int r = h * 16 + i;
        const char* src = (const char*)KV + (size_t)(start + r) * 1024;
        int sb = (ln * 16) ^ ((r & 7) << 4);
        gload_lds16(src + sb, kv + r * 1024 + ln * 16);
    }
    qs[t] = Q[(size_t)b * 256 + t];
    __syncthreads();

    // hoist q (this head's 64 floats) to registers
    float2 qreg[32];
    #pragma unroll
    for (int j = 0; j < 32; ++j)
        qreg[j] = *(const float2*)(qs + h * 64 + 2 * j);

    // score: lane ln = neighbor index
    float sx = 0.f, sy = 0.f;
    {
        const char* krow = kv + ln * 1024;
        const int sw = (ln & 7) << 4;
        #pragma unroll
        for (int j8 = 0; j8 < 8; ++j8) {
            bf16x8 kf = *(const bf16x8*)(krow + (((h * 128) + j8 * 16) ^ sw));
            #pragma unroll
            for (int p = 0; p < 4; ++p) {
                float2 q2 = qreg[j8 * 4 + p];
                sx = fmaf(q2.x, bf2f((unsigned short)kf[2 * p]), sx);
                sy = fmaf(q2.y, bf2f((unsigned short)kf[2 * p + 1]), sy);
            }
        }
    }
    float s = (ln < len) ? (sx + sy) : -3.0e38f;
    float mx = s;
    #pragma unroll
    for (int off = 32; off; off >>= 1) mx = fmaxf(mx, __shfl_xor(mx, off));
    float e = (ln < len) ? __expf(s - mx) : 0.f;
    float sum = e;
    #pragma unroll
    for (int off = 32; off; off >>= 1) sum += __shfl_xor(sum, off);
    awl[h * 64 + ln] = e / sum;
    __syncthreads();

    // PV: halves of the wave handle m in [0,32) and [32,64); lane covers dims 2dl,2dl+1
    const int half = ln >> 5, dl = ln & 31;
    float a0 = 0.f, a1 = 0.f;
    {
        const char* vbase = kv + half * 32768;   // half*32 rows * 1024
        const int voff = 512 + h * 128 + dl * 4;
        #pragma unroll
        for (int mm = 0; mm < 32; ++mm) {
            unsigned int vv = *(const unsigned int*)(vbase + mm * 1024 + (voff ^ ((mm & 7) << 4)));
            float awm = awl[h * 64 + half * 32 + mm];
            float lo = __builtin_bit_cast(float, vv << 16);
            float hi = __builtin_bit_cast(float, vv & 0xFFFF0000u);
            a0 = fmaf(awm, lo, a0);
            a1 = fmaf(awm, hi, a1);
        }
    }
    a0 += __shfl_xor(a0, 32);
    a1 += __shfl_xor(a1, 32);
    if (ln < 32) {
        float2 o; o.x = a0; o.y = a1;
        *(float2*)(out + (size_t)b * 256 + h * 64 + 2 * dl) = o;
    }
}

extern "C" void kernel_launch(void* const* d_in, const int* in_sizes, int n_in,
                              void* d_out, int out_size, void* d_ws, size_t ws_size,
                              hipStream_t stream) {
    const float* enc    = (const float*)d_in[0];
    const float* social = (const float*)d_in[1];
    const float* Wq = (const float*)d_in[2];
    const float* bq = (const float*)d_in[3];
    const float* Wk = (const float*)d_in[4];
    const float* bk = (const float*)d_in[5];
    const float* Wv = (const float*)d_in[6];
    const float* bv = (const float*)d_in[7];
    const float* Wf = (const float*)d_in[8];
    const float* bf = (const float*)d_in[9];
    const int* st = (const int*)d_in[10];
    const int* en = (const int*)d_in[11];
    (void)in_sizes; (void)n_in; (void)out_size; (void)ws_size;

    char* ws = (char*)d_ws;
    unsigned short* KV = (unsigned short*)ws;                       // 128 MB
    float* Qb    = (float*)(ws + 134217728);                        // 4 MB
    float* attnb = (float*)(ws + 134217728 + 4194304);              // 4 MB
    float* outf  = (float*)d_out;

    kv_gemm_rb<<<dim3(256), dim3(512), 0, stream>>>(social, Wk, bk, Wv, bv, KV);
    gemm_proj<0, 1><<<dim3(32, 4), dim3(256), 0, stream>>>(enc, 4096, Wq, bq, nullptr, nullptr, Qb, 256, 0.0625f);
    attn_kernel<<<dim3(4096), dim3(256), 67584, stream>>>(Qb, KV, st, en, attnb);
    gemm_proj<0, 0><<<dim3(32, 4), dim3(256), 0, stream>>>(attnb, 4096, Wf, bf, nullptr, nullptr, outf, 256, 1.0f);
}